// Round 16
// baseline (126.240 us; speedup 1.0000x reference)
//
#include <hip/hip_runtime.h>
#include <math.h>
#include <stdint.h>

// ---- problem constants ----
#define DMODEL 2048
#define DINNER 2457
#define NI     2464      // padded row stride for [*, DINNER] buffers (=7*352)
#define GROUPS 7
#define GCH    351       // channels per group
#define GP     352       // K-padded channels per group (bf16 layouts)
#define GNP    384       // N-padded channels per group (conv B rows)
#define NROW_XI 1152     // 18*64 rows (t=110..127)
#define NROW_Z  512      // 8*64 rows (t=120..127)
#define NCAT   5120      // fused GEMM N: W_in -> [0,2560), W_gate -> [2560,5120)
#define GATE0  2560
#define OUT_SPLITS 16
#define CONV_PLANE (GROUPS * GNP * GP)   // per-tap conv-B plane elems (2688*352)

typedef __attribute__((ext_vector_type(8))) __bf16 bf16x8;
typedef __attribute__((ext_vector_type(4))) float f32x4;
typedef __attribute__((ext_vector_type(8))) unsigned short ushort8;

__device__ inline unsigned short f2bf(float f) {
    union { float f; unsigned int u; } v; v.f = f;
    unsigned int u = v.u;
    return (unsigned short)((u + 0x7FFFu + ((u >> 16) & 1u)) >> 16);  // RNE
}

// LDS swizzle: rows of 32 shorts (64B = 4x16B slots); LDS position p of row r
// holds global slot p ^ ((r>>1)&3). Source pre-swizzled, read swizzled (rule #21).
__device__ inline int lds_addr(int row, int slot) {
    return row * 32 + ((slot ^ ((row >> 1) & 3)) << 3);
}

// async global->LDS, 16B per lane; lds dest is wave-uniform base + lane*16
__device__ __forceinline__ void gload16(const unsigned short* g, unsigned short* l) {
    __builtin_amdgcn_global_load_lds(
        (const __attribute__((address_space(1))) unsigned int*)g,
        (__attribute__((address_space(3))) unsigned int*)l, 16, 0, 0);
}

// ---------------- casts: x slice + W_in|W_gate (conv weights cast in gemm) --
#define CAST_B0 1152
#define CAST_B1 6066
__global__ __launch_bounds__(256)
void cast_all(const float* __restrict__ x110,
              const float* __restrict__ Win, const float* __restrict__ Wg,
              unsigned short* __restrict__ A_x,
              unsigned short* __restrict__ B_cat)
{
    int bx = blockIdx.x;
    if (bx < CAST_B0) {
        size_t t = (size_t)bx * 256 + threadIdx.x;
        const float4* s = (const float4*)x110 + t * 2;
        float4 a = s[0], b = s[1];
        ushort8 o;
        o[0]=f2bf(a.x); o[1]=f2bf(a.y); o[2]=f2bf(a.z); o[3]=f2bf(a.w);
        o[4]=f2bf(b.x); o[5]=f2bf(b.y); o[6]=f2bf(b.z); o[7]=f2bf(b.w);
        *(ushort8*)(A_x + t * 8) = o;
    } else {
        int idx = bx - CAST_B0;
        int half = idx >= DINNER;
        int cb = half ? idx - DINNER : idx;
        const float* src = half ? Wg : Win;
        size_t t = (size_t)cb * 256 + threadIdx.x;
        size_t elem = t * 8;
        size_t doff = elem + (half ? (size_t)GATE0 * DMODEL : 0);
        const float4* s = (const float4*)(src + elem);
        float4 a = s[0], b = s[1];
        ushort8 o;
        o[0]=f2bf(a.x); o[1]=f2bf(a.y); o[2]=f2bf(a.z); o[3]=f2bf(a.w);
        o[4]=f2bf(b.x); o[5]=f2bf(b.y); o[6]=f2bf(b.z); o[7]=f2bf(b.w);
        *(ushort8*)(B_cat + doff) = o;
    }
}

// ---------------- fused xi|z bf16 MFMA GEMM + overlapped conv-weight cast ---
// tile 128x128, 4 waves (wave-tile 64x64). Depth-3 counted-vmcnt pipeline,
// 4 LDS buffers (64KB -> 2 blocks/CU), one raw barrier per K-step,
// vmcnt(8) steady state. Blocks >= 260 grid-stride the conv-weight cast.
#define NKF 64   // 2048/32
#define GEMM_BLKS 260
#define CAST_BLKS 224
__global__ __launch_bounds__(256)
void gemm_mfma_fused(const unsigned short* __restrict__ A,   // [1152][2048] bf16
                     const unsigned short* __restrict__ B,   // [5120][2048] bf16
                     const float* __restrict__ Wc,           // [2457][351][4] f32
                     const float* __restrict__ b_in,
                     const float* __restrict__ b_gate,
                     unsigned short* __restrict__ xi,        // [1152][NI] bf16 group-padded
                     float* __restrict__ zb,                 // [512][NI] f32
                     unsigned short* __restrict__ B_cv)      // [4][2688][352] bf16
{
    __shared__ unsigned short sm[4 * 256 * 32];   // 4 bufs x (A128 + B128 rows) x 64B = 64KB
    const int tid = threadIdx.x;
    const int orig = blockIdx.x;

    if (orig >= GEMM_BLKS) {      // ---- conv-weight cast path (fills idle CUs)
        for (int t = (orig - GEMM_BLKS) * 256 + tid; t < DINNER * GCH;
             t += CAST_BLKS * 256) {
            int oc = t / GCH, i = t - oc * GCH;
            float4 w4 = *(const float4*)(Wc + (size_t)t * 4);
            int g = oc / GCH, ol = oc - g * GCH;
            size_t base = (size_t)(g * GNP + ol) * GP + i;
            B_cv[0 * (size_t)CONV_PLANE + base] = f2bf(w4.x);
            B_cv[1 * (size_t)CONV_PLANE + base] = f2bf(w4.y);
            B_cv[2 * (size_t)CONV_PLANE + base] = f2bf(w4.z);
            B_cv[3 * (size_t)CONV_PLANE + base] = f2bf(w4.w);
            if (i == GCH - 1) {
                B_cv[0 * (size_t)CONV_PLANE + base + 1] = 0;
                B_cv[1 * (size_t)CONV_PLANE + base + 1] = 0;
                B_cv[2 * (size_t)CONV_PLANE + base + 1] = 0;
                B_cv[3 * (size_t)CONV_PLANE + base + 1] = 0;
            }
        }
        return;
    }

    const int w = tid >> 6, l = tid & 63;
    const int l15 = l & 15, l4 = l >> 4;
    const int wm = w >> 1, wn = w & 1;

    // bijective XCD-chunked swizzle (260 = 8*32+4); logical n-major.
    const int xcd = orig & 7, lo = orig >> 3;
    const int logical = (xcd < 4 ? xcd * 33 : 132 + (xcd - 4) * 32) + lo;
    int mt, nt, is_gate;
    if (logical < 180) { nt = logical / 9; mt = logical % 9; is_gate = 0; }
    else { int b2 = logical - 180; nt = 20 + b2 / 4; mt = 5 + b2 % 4; is_gate = 1; }
    const int m0 = mt * 128, n0 = nt * 128;

    // staging: seg = 16 rows (1KB); wave w stages A segs {w,w+4}, B segs {w,w+4}
    const int lr = l >> 2, slot = l & 3;
    const int r0 = w * 16 + lr, r1 = r0 + 64;
    const int xo0 = (slot ^ ((r0 >> 1) & 3)) << 3;
    const int xo1 = (slot ^ ((r1 >> 1) & 3)) << 3;
    const unsigned short* gA0 = A + (size_t)(m0 + r0) * DMODEL + xo0;
    const unsigned short* gA1 = A + (size_t)(m0 + r1) * DMODEL + xo1;
    const unsigned short* gB0 = B + (size_t)(n0 + r0) * DMODEL + xo0;
    const unsigned short* gB1 = B + (size_t)(n0 + r1) * DMODEL + xo1;
    unsigned short* dA0 = sm + w * 512;
    unsigned short* dA1 = sm + (w + 4) * 512;
    unsigned short* dB0 = sm + 4096 + w * 512;
    unsigned short* dB1 = sm + 4096 + (w + 4) * 512;

#define STAGE_G(buf, ks) do { int _o = (ks) * 32, _b = (buf) * 8192; \
    gload16(gA0 + _o, dA0 + _b); gload16(gA1 + _o, dA1 + _b); \
    gload16(gB0 + _o, dB0 + _b); gload16(gB1 + _o, dB1 + _b); } while (0)

    f32x4 acc[4][4] = {};
    auto compute = [&](const unsigned short* base) {
        bf16x8 af[4], bfr[4];
#pragma unroll
        for (int f = 0; f < 4; ++f)
            af[f] = *(const bf16x8*)(base + lds_addr(wm * 64 + f * 16 + l15, l4));
#pragma unroll
        for (int j = 0; j < 4; ++j)
            bfr[j] = *(const bf16x8*)(base + 4096 + lds_addr(wn * 64 + j * 16 + l15, l4));
        __builtin_amdgcn_s_setprio(1);
#pragma unroll
        for (int i = 0; i < 4; ++i)
#pragma unroll
            for (int j = 0; j < 4; ++j)
                acc[i][j] = __builtin_amdgcn_mfma_f32_16x16x32_bf16(af[i], bfr[j], acc[i][j], 0, 0, 0);
        __builtin_amdgcn_s_setprio(0);
    };

    STAGE_G(0, 0); STAGE_G(1, 1); STAGE_G(2, 2);
    int rbuf = 0, sbuf = 3;
    for (int ks = 0; ks < NKF - 3; ++ks) {
        asm volatile("s_waitcnt vmcnt(8)" ::: "memory");    // tile-ks loads done
        __builtin_amdgcn_s_barrier();
        STAGE_G(sbuf, ks + 3);                              // keep 3 tiles in flight
        compute(sm + rbuf * 8192);
        rbuf = (rbuf + 1) & 3;
        sbuf = (sbuf + 1) & 3;
    }
    asm volatile("s_waitcnt vmcnt(8)" ::: "memory");
    __builtin_amdgcn_s_barrier();
    compute(sm + rbuf * 8192); rbuf = (rbuf + 1) & 3;
    asm volatile("s_waitcnt vmcnt(4)" ::: "memory");
    __builtin_amdgcn_s_barrier();
    compute(sm + rbuf * 8192); rbuf = (rbuf + 1) & 3;
    asm volatile("s_waitcnt vmcnt(0)" ::: "memory");
    __builtin_amdgcn_s_barrier();
    compute(sm + rbuf * 8192);
#undef STAGE_G

    if (!is_gate) {
#pragma unroll
        for (int j = 0; j < 4; ++j) {
            int colg = n0 + wn * 64 + j * 16 + l15;
            if (colg < DINNER) {
                int g = colg / GCH, ci = colg - g * GCH;
                float bias = b_in[colg];
                size_t dco = (size_t)(g * GP + ci);
#pragma unroll
                for (int i = 0; i < 4; ++i)
#pragma unroll
                    for (int r = 0; r < 4; ++r) {
                        int row = m0 + wm * 64 + i * 16 + l4 * 4 + r;
                        xi[(size_t)row * NI + dco] = f2bf(acc[i][j][r] + bias);
                        if (ci == GCH - 1) xi[(size_t)row * NI + dco + 1] = 0;  // K-pad
                    }
            }
        }
    } else {
#pragma unroll
        for (int j = 0; j < 4; ++j) {
            int ng = n0 + wn * 64 + j * 16 + l15 - GATE0;
            if (ng < DINNER) {
                float bias = b_gate[ng];
#pragma unroll
                for (int i = 0; i < 4; ++i)
#pragma unroll
                    for (int r = 0; r < 4; ++r) {
                        int row = m0 + wm * 64 + i * 16 + l4 * 4 + r;  // >= 640 always
                        zb[(size_t)(row - 640) * NI + ng] = acc[i][j][r] + bias;
                    }
            }
        }
    }
}

// ---------------- grouped causal conv: 4 shifted-tap MFMA GEMMs + SiLU ------
// tile 64x128, 4 waves (wave-tile 32x64); depth-4 counted-vmcnt, 5 buffers.
#define NKC 44
__global__ __launch_bounds__(256)
void conv_mfma(const unsigned short* __restrict__ xi,  // [1152][NI] bf16
               const unsigned short* __restrict__ Bc,  // [4][2688][352] bf16
               const float* __restrict__ bc,
               float* __restrict__ xcb)                // [960][NI] f32 (post-SiLU)
{
    __shared__ unsigned short sm[5 * 192 * 32];   // 5 bufs x (A64 + B128 rows) x 64B = 60KB
    const int tid = threadIdx.x;
    const int w = tid >> 6, l = tid & 63;
    const int l15 = l & 15, l4 = l >> 4;
    const int wm = w >> 1, wn = w & 1;

    // bijective XCD-chunked swizzle (315 = 8*39+3)
    const int orig = blockIdx.x;
    const int xcd = orig & 7, lo = orig >> 3;
    const int logical = (xcd < 3 ? xcd * 40 : 120 + (xcd - 3) * 39) + lo;
    const int gn = logical / 15, mt = logical % 15;
    const int g = gn / 3, nt = gn % 3;
    const int m0 = mt * 64;
    const int n0l = nt * 128;

    const int lr = l >> 2, slot = l & 3;
    const int rA = w * 16 + lr;            // A rows 0..63 (seg w)
    const int rB1 = rA + 64;               // B segs w, w+4
    const int xoA  = (slot ^ ((rA  >> 1) & 3)) << 3;
    const int xoB1 = (slot ^ ((rB1 >> 1) & 3)) << 3;
    const unsigned short* gAb = xi + (size_t)(m0 + rA) * NI + g * GP + xoA;
    const unsigned short* gB0 = Bc + (size_t)(g * GNP + n0l + rA) * GP + xoA;
    const unsigned short* gB1 = Bc + (size_t)(g * GNP + n0l + rB1) * GP + xoB1;
    unsigned short* dA  = sm + w * 512;
    unsigned short* dB0 = sm + 2048 + w * 512;
    unsigned short* dB1 = sm + 2048 + (w + 4) * 512;

#define STAGE_C(buf, ks) do { \
    int _tap = (ks) / 11, _kc = (ks) - _tap * 11, _b = (buf) * 6144; \
    size_t _ao = (size_t)(64 * _tap) * NI + _kc * 32; \
    size_t _bo = (size_t)_tap * CONV_PLANE + _kc * 32; \
    gload16(gAb + _ao, dA  + _b); \
    gload16(gB0 + _bo, dB0 + _b); \
    gload16(gB1 + _bo, dB1 + _b); } while (0)

    f32x4 acc[2][4] = {};
    auto compute = [&](const unsigned short* base) {
        bf16x8 af[2], bfr[4];
#pragma unroll
        for (int f = 0; f < 2; ++f)
            af[f] = *(const bf16x8*)(base + lds_addr(wm * 32 + f * 16 + l15, l4));
#pragma unroll
        for (int j = 0; j < 4; ++j)
            bfr[j] = *(const bf16x8*)(base + 2048 + lds_addr(wn * 64 + j * 16 + l15, l4));
        __builtin_amdgcn_s_setprio(1);
#pragma unroll
        for (int i = 0; i < 2; ++i)
#pragma unroll
            for (int j = 0; j < 4; ++j)
                acc[i][j] = __builtin_amdgcn_mfma_f32_16x16x32_bf16(af[i], bfr[j], acc[i][j], 0, 0, 0);
        __builtin_amdgcn_s_setprio(0);
    };

    STAGE_C(0, 0); STAGE_C(1, 1); STAGE_C(2, 2); STAGE_C(3, 3);
    int rbuf = 0, sbuf = 4;
    for (int ks = 0; ks < NKC - 4; ++ks) {
        asm volatile("s_waitcnt vmcnt(9)" ::: "memory");
        __builtin_amdgcn_s_barrier();
        STAGE_C(sbuf, ks + 4);
        compute(sm + rbuf * 6144);
        rbuf = rbuf == 4 ? 0 : rbuf + 1;
        sbuf = sbuf == 4 ? 0 : sbuf + 1;
    }
    asm volatile("s_waitcnt vmcnt(9)" ::: "memory");
    __builtin_amdgcn_s_barrier();
    compute(sm + rbuf * 6144); rbuf = rbuf == 4 ? 0 : rbuf + 1;
    asm volatile("s_waitcnt vmcnt(6)" ::: "memory");
    __builtin_amdgcn_s_barrier();
    compute(sm + rbuf * 6144); rbuf = rbuf == 4 ? 0 : rbuf + 1;
    asm volatile("s_waitcnt vmcnt(3)" ::: "memory");
    __builtin_amdgcn_s_barrier();
    compute(sm + rbuf * 6144); rbuf = rbuf == 4 ? 0 : rbuf + 1;
    asm volatile("s_waitcnt vmcnt(0)" ::: "memory");
    __builtin_amdgcn_s_barrier();
    compute(sm + rbuf * 6144);
#undef STAGE_C

#pragma unroll
    for (int j = 0; j < 4; ++j) {
        int ocl = n0l + wn * 64 + j * 16 + l15;
        if (ocl < GCH) {
            int ch = g * GCH + ocl;
            float bias = bc[ch];
#pragma unroll
            for (int i = 0; i < 2; ++i)
#pragma unroll
                for (int r = 0; r < 4; ++r) {
                    int row = m0 + wm * 32 + i * 16 + l4 * 4 + r;
                    float v = acc[i][j][r] + bias;
                    xcb[(size_t)row * NI + ch] = v / (1.f + expf(-v));
                }
        }
    }
}

// ---------------- xp only: one block per row (512 rows, proven) ------------
__global__ __launch_bounds__(256)
void xp_kernel(const float* __restrict__ xc,    // [960][NI], rows 448.. = t 24..31
               const float* __restrict__ Wxp,   // [48][DINNER]
               const float* __restrict__ bxp,
               float* __restrict__ xp32)        // [512][32]
{
    const int row = blockIdx.x;
    const float* a = xc + (size_t)(448 + row) * NI;
    float acc[32];
#pragma unroll
    for (int o = 0; o < 32; ++o) acc[o] = 0.f;
    for (int k = threadIdx.x; k < DINNER; k += 256) {
        float av = a[k];
#pragma unroll
        for (int o = 0; o < 32; ++o)
            acc[o] = fmaf(av, Wxp[(size_t)o * DINNER + k], acc[o]);
    }
#pragma unroll
    for (int o = 0; o < 32; ++o)
#pragma unroll
        for (int off = 32; off; off >>= 1)
            acc[o] += __shfl_down(acc[o], off);
    __shared__ float red[4][32];
    const int wid = threadIdx.x >> 6, lane = threadIdx.x & 63;
    if (lane == 0)
#pragma unroll
        for (int o = 0; o < 32; ++o) red[wid][o] = acc[o];
    __syncthreads();
    if (threadIdx.x < 32) {
        int o = threadIdx.x;
        xp32[row * 32 + o] = red[0][o] + red[1][o] + red[2][o] + red[3][o] + bxp[o];
    }
}

// ---------------- window-softmax + inline dt + gate + mean over last 8 steps
__global__ __launch_bounds__(256)
void fuse_kernel(const float* __restrict__ xc, const float* __restrict__ z,
                 const float* __restrict__ xp,   // [512][32]
                 const float* __restrict__ Wdt,  // [DINNER][32]
                 const float* __restrict__ Dp,
                 float* __restrict__ comp)
{
    const int d = blockIdx.x * 256 + threadIdx.x;
    const int b = blockIdx.y;
    __shared__ float xps[8][32];
    {   // stage the 8 xp rows for this batch b (8*32 = 256 values, one per thread)
        int s = threadIdx.x >> 5, o = threadIdx.x & 31;
        xps[s][o] = xp[((s * 64) + b) * 32 + o];
    }
    __syncthreads();
    if (d >= DINNER) return;
    float wd[32];
    {
        const float4* wp = (const float4*)(Wdt + (size_t)d * 32);
#pragma unroll
        for (int q = 0; q < 8; ++q) {
            float4 v = wp[q];
            wd[q * 4 + 0] = v.x; wd[q * 4 + 1] = v.y;
            wd[q * 4 + 2] = v.z; wd[q * 4 + 3] = v.w;
        }
    }
    float xcv[15];
#pragma unroll
    for (int tt = 0; tt < 15; ++tt) xcv[tt] = xc[(size_t)(tt * 64 + b) * NI + d];
    const float Dpd = Dp[d];
    float acc = 0.f;
#pragma unroll
    for (int s = 0; s < 8; ++s) {
        float sv = 0.f;
#pragma unroll
        for (int k = 0; k < 32; ++k) sv = fmaf(xps[s][k], wd[k], sv);
        float dval = fmaxf(sv, 0.f) + log1pf(expf(-fabsf(sv))) + 1e-4f;  // softplus+eps
        float zval = z[(size_t)(s * 64 + b) * NI + d];
        float e = expf(-dval);
        float w = 1.f, wsum = 0.f, lsum = 0.f;
#pragma unroll
        for (int k = 7; k >= 0; --k) {
            wsum += w;
            lsum = fmaf(w, xcv[s + k], lsum);
            w *= e;
        }
        float local = lsum / wsum;
        float ys = (local + Dpd * xcv[s + 7]) / (1.f + expf(-zval));
        acc += ys;
    }
    comp[(size_t)b * NI + d] = acc * 0.125f;
}

// ---------------- split-K out-projection (f32)
__global__ __launch_bounds__(256)
void gemm_nt_splitk(const float* __restrict__ A, int lda,
                    const float* __restrict__ B, int ldb,
                    float* __restrict__ Cp, int ldc,
                    int M, int N, int K, int kchunk)
{
    __shared__ float As[16][68];
    __shared__ float Bs[16][68];
    const int tid = threadIdx.x;
    const int tx = tid & 15, ty = tid >> 4;
    const int m0 = blockIdx.y * 64, n0 = blockIdx.x * 64;
    const int kbeg = blockIdx.z * kchunk;
    const int kend = min(K, kbeg + kchunk);
    float* C = Cp + (size_t)blockIdx.z * M * ldc;
    float acc[4][4] = {};
    for (int k0 = kbeg; k0 < kend; k0 += 16) {
#pragma unroll
        for (int u = 0; u < 4; ++u) {
            int idx = u * 256 + tid;
            int r = idx >> 4, kk = idx & 15;
            int gk = k0 + kk;
            float av = 0.f, bv = 0.f;
            if (gk < kend) {
                av = A[(size_t)(m0 + r) * lda + gk];
                int nn = n0 + r;
                bv = (nn < N) ? B[(size_t)nn * ldb + gk] : 0.f;
            }
            As[kk][r] = av;
            Bs[kk][r] = bv;
        }
        __syncthreads();
#pragma unroll
        for (int kk = 0; kk < 16; ++kk) {
            float4 a4 = *(const float4*)&As[kk][ty * 4];
            float4 b4 = *(const float4*)&Bs[kk][tx * 4];
            float a[4] = {a4.x, a4.y, a4.z, a4.w};
            float b[4] = {b4.x, b4.y, b4.z, b4.w};
#pragma unroll
            for (int i = 0; i < 4; ++i)
#pragma unroll
                for (int j = 0; j < 4; ++j)
                    acc[i][j] = fmaf(a[i], b[j], acc[i][j]);
        }
        __syncthreads();
    }
#pragma unroll
    for (int i = 0; i < 4; ++i) {
        int m = m0 + ty * 4 + i;
#pragma unroll
        for (int j = 0; j < 4; ++j) {
            int n = n0 + tx * 4 + j;
            if (n < N) C[(size_t)m * ldc + n] = acc[i][j];
        }
    }
}

// ---------------- splitk-reduce + bias + layernorm fused (1024 threads) -----
__global__ __launch_bounds__(1024)
void ln_kernel(const float* __restrict__ Cp,    // [16][64][2048] partials
               const float* __restrict__ b_out,
               const float* __restrict__ lw, const float* __restrict__ lb,
               float* __restrict__ out)
{
    const int b = blockIdx.x;
    const int tid = threadIdx.x;     // 0..1023 (16 waves)
    __shared__ float red[16];
    float v[2];
    float s = 0.f;
#pragma unroll
    for (int i = 0; i < 2; ++i) {
        int col = i * 1024 + tid;
        float acc = b_out[col];
#pragma unroll
        for (int p = 0; p < OUT_SPLITS; ++p)
            acc += Cp[(size_t)p * 64 * 2048 + b * 2048 + col];
        v[i] = acc; s += acc;
    }
#pragma unroll
    for (int off = 32; off; off >>= 1) s += __shfl_down(s, off);
    if ((tid & 63) == 0) red[tid >> 6] = s;
    __syncthreads();
    float mu = 0.f;
#pragma unroll
    for (int q = 0; q < 16; ++q) mu += red[q];
    mu /= 2048.f;
    float s2 = 0.f;
#pragma unroll
    for (int i = 0; i < 2; ++i) { float dd = v[i] - mu; s2 += dd * dd; }
#pragma unroll
    for (int off = 32; off; off >>= 1) s2 += __shfl_down(s2, off);
    __syncthreads();
    if ((tid & 63) == 0) red[tid >> 6] = s2;
    __syncthreads();
    float var = 0.f;
#pragma unroll
    for (int q = 0; q < 16; ++q) var += red[q];
    var /= 2048.f;
    float inv = rsqrtf(var + 1e-5f);
#pragma unroll
    for (int i = 0; i < 2; ++i) {
        int dcol = i * 1024 + tid;
        out[b * 2048 + dcol] = (v[i] - mu) * inv * lw[dcol] + lb[dcol];
    }
}

extern "C" void kernel_launch(void* const* d_in, const int* in_sizes, int n_in,
                              void* d_out, int out_size, void* d_ws, size_t ws_size,
                              hipStream_t stream)
{
    const float* x      = (const float*)d_in[0];
    const float* W_in   = (const float*)d_in[1];
    const float* b_in   = (const float*)d_in[2];
    const float* W_gate = (const float*)d_in[3];
    const float* b_gate = (const float*)d_in[4];
    const float* W_conv = (const float*)d_in[5];
    const float* b_conv = (const float*)d_in[6];
    const float* W_xp   = (const float*)d_in[7];
    const float* b_xp   = (const float*)d_in[8];
    const float* W_dt   = (const float*)d_in[9];
    const float* Dp     = (const float*)d_in[10];
    const float* W_out  = (const float*)d_in[11];
    const float* b_out  = (const float*)d_in[12];
    const float* ln_w   = (const float*)d_in[13];
    const float* ln_b   = (const float*)d_in[14];
    float* out = (float*)d_out;

    float* ws = (float*)d_ws;
    auto alloc = [&](size_t nf) { float* p = ws; ws += (nf + 255) & ~(size_t)255; return p; };
    unsigned short* A_x   = (unsigned short*)alloc((size_t)NROW_XI * DMODEL / 2);
    unsigned short* B_cat = (unsigned short*)alloc((size_t)NCAT * DMODEL / 2);
    unsigned short* B_cv  = (unsigned short*)alloc((size_t)4 * CONV_PLANE / 2);
    unsigned short* xi_bf = (unsigned short*)alloc((size_t)NROW_XI * NI / 2);
    float* zb   = alloc((size_t)NROW_Z * NI);
    float* xp32 = alloc((size_t)512 * 32);
    float* comp = alloc((size_t)64 * NI);
    // aliases (stream-ordered lifetime):
    float* xcb     = (float*)B_cat;                    // 960*NI f32, after fused GEMM done
    float* outpart = (float*)B_cat + (size_t)960 * NI; // 16*64*2048 f32, disjoint from xcb

    // 1) casts (x slice + W_in|W_gate); conv weights cast inside gemm kernel
    cast_all<<<CAST_B1, 256, 0, stream>>>(x + (size_t)(110 * 64) * DMODEL,
                                          W_in, W_gate, A_x, B_cat);
    // 2) fused xi|z MFMA GEMM (260 tiles, 64KB LDS -> 2 blocks/CU) + conv-cast
    gemm_mfma_fused<<<GEMM_BLKS + CAST_BLKS, 256, 0, stream>>>(
        A_x, B_cat, W_conv, b_in, b_gate, xi_bf, zb, B_cv);
    // 3) conv MFMA + SiLU
    conv_mfma<<<315, 256, 0, stream>>>(xi_bf, B_cv, b_conv, xcb);
    // 4) xp projection, then window-softmax fuse with inline dt
    xp_kernel<<<512, 256, 0, stream>>>(xcb, W_xp, b_xp, xp32);
    {
        dim3 grid((DINNER + 255) / 256, 64);
        fuse_kernel<<<grid, 256, 0, stream>>>(xcb, zb, xp32, W_dt, Dp, comp);
    }
    // 5) out-projection (split-K 16) + fused reduce+LN (1024-thread blocks)
    {
        const int kchunk = (DINNER + OUT_SPLITS - 1) / OUT_SPLITS;  // 154
        dim3 grid(DMODEL / 64, 1, OUT_SPLITS);
        gemm_nt_splitk<<<grid, 256, 0, stream>>>(comp, NI, W_out, DINNER,
                                                 outpart, DMODEL, 64, DMODEL, DINNER, kchunk);
    }
    ln_kernel<<<64, 1024, 0, stream>>>(outpart, b_out, ln_w, ln_b, out);
}

// Round 17
// 123.861 us; speedup vs baseline: 1.0192x; 1.0192x over previous
//
#include <hip/hip_runtime.h>
#include <math.h>
#include <stdint.h>

// ---- problem constants ----
#define DMODEL 2048
#define DINNER 2457
#define NI     2464      // padded row stride for [*, DINNER] buffers (=7*352)
#define GROUPS 7
#define GCH    351       // channels per group
#define GP     352       // K-padded channels per group (bf16 layouts)
#define GNP    384       // N-padded channels per group (conv B rows)
#define NROW_XI 1152     // 18*64 rows (t=110..127)
#define NROW_Z  512      // 8*64 rows (t=120..127)
#define NCAT   5120      // fused GEMM N: W_in -> [0,2560), W_gate -> [2560,5120)
#define GATE0  2560
#define OUT_SPLITS 16
#define CONV_PLANE (GROUPS * GNP * GP)   // per-tap conv-B plane elems (2688*352)

typedef __attribute__((ext_vector_type(8))) __bf16 bf16x8;
typedef __attribute__((ext_vector_type(4))) float f32x4;
typedef __attribute__((ext_vector_type(8))) unsigned short ushort8;

__device__ inline unsigned short f2bf(float f) {
    union { float f; unsigned int u; } v; v.f = f;
    unsigned int u = v.u;
    return (unsigned short)((u + 0x7FFFu + ((u >> 16) & 1u)) >> 16);  // RNE
}

// LDS swizzle: rows of 32 shorts (64B = 4x16B slots); LDS position p of row r
// holds global slot p ^ ((r>>1)&3). Source pre-swizzled, read swizzled (rule #21).
__device__ inline int lds_addr(int row, int slot) {
    return row * 32 + ((slot ^ ((row >> 1) & 3)) << 3);
}

// async global->LDS, 16B per lane; lds dest is wave-uniform base + lane*16
__device__ __forceinline__ void gload16(const unsigned short* g, unsigned short* l) {
    __builtin_amdgcn_global_load_lds(
        (const __attribute__((address_space(1))) unsigned int*)g,
        (__attribute__((address_space(3))) unsigned int*)l, 16, 0, 0);
}

// ---------------- casts: x slice + W_in|W_gate (conv weights cast in gemm) --
#define CAST_B0 1152
#define CAST_B1 6066
__global__ __launch_bounds__(256)
void cast_all(const float* __restrict__ x110,
              const float* __restrict__ Win, const float* __restrict__ Wg,
              unsigned short* __restrict__ A_x,
              unsigned short* __restrict__ B_cat)
{
    int bx = blockIdx.x;
    if (bx < CAST_B0) {
        size_t t = (size_t)bx * 256 + threadIdx.x;
        const float4* s = (const float4*)x110 + t * 2;
        float4 a = s[0], b = s[1];
        ushort8 o;
        o[0]=f2bf(a.x); o[1]=f2bf(a.y); o[2]=f2bf(a.z); o[3]=f2bf(a.w);
        o[4]=f2bf(b.x); o[5]=f2bf(b.y); o[6]=f2bf(b.z); o[7]=f2bf(b.w);
        *(ushort8*)(A_x + t * 8) = o;
    } else {
        int idx = bx - CAST_B0;
        int half = idx >= DINNER;
        int cb = half ? idx - DINNER : idx;
        const float* src = half ? Wg : Win;
        size_t t = (size_t)cb * 256 + threadIdx.x;
        size_t elem = t * 8;
        size_t doff = elem + (half ? (size_t)GATE0 * DMODEL : 0);
        const float4* s = (const float4*)(src + elem);
        float4 a = s[0], b = s[1];
        ushort8 o;
        o[0]=f2bf(a.x); o[1]=f2bf(a.y); o[2]=f2bf(a.z); o[3]=f2bf(a.w);
        o[4]=f2bf(b.x); o[5]=f2bf(b.y); o[6]=f2bf(b.z); o[7]=f2bf(b.w);
        *(ushort8*)(B_cat + doff) = o;
    }
}

// ---------------- fused xi|z bf16 MFMA GEMM + overlapped conv-weight cast ---
// tile 128x128, 4 waves (wave-tile 64x64). Depth-4 counted-vmcnt pipeline,
// 5 LDS buffers (80KB), one raw barrier per K-step, vmcnt(12) steady state.
// Blocks >= 260 grid-stride the conv-weight f32->bf16 cast (fills idle CUs).
#define NKF 64   // 2048/32
#define GEMM_BLKS 260
#define CAST_BLKS 224
__global__ __launch_bounds__(256)
void gemm_mfma_fused(const unsigned short* __restrict__ A,   // [1152][2048] bf16
                     const unsigned short* __restrict__ B,   // [5120][2048] bf16
                     const float* __restrict__ Wc,           // [2457][351][4] f32
                     const float* __restrict__ b_in,
                     const float* __restrict__ b_gate,
                     unsigned short* __restrict__ xi,        // [1152][NI] bf16 group-padded
                     float* __restrict__ zb,                 // [512][NI] f32
                     unsigned short* __restrict__ B_cv)      // [4][2688][352] bf16
{
    __shared__ unsigned short sm[5 * 256 * 32];   // 5 bufs x (A128 + B128 rows) x 64B = 80KB
    const int tid = threadIdx.x;
    const int orig = blockIdx.x;

    if (orig >= GEMM_BLKS) {      // ---- conv-weight cast path (fills idle CUs)
        for (int t = (orig - GEMM_BLKS) * 256 + tid; t < DINNER * GCH;
             t += CAST_BLKS * 256) {
            int oc = t / GCH, i = t - oc * GCH;
            float4 w4 = *(const float4*)(Wc + (size_t)t * 4);
            int g = oc / GCH, ol = oc - g * GCH;
            size_t base = (size_t)(g * GNP + ol) * GP + i;
            B_cv[0 * (size_t)CONV_PLANE + base] = f2bf(w4.x);
            B_cv[1 * (size_t)CONV_PLANE + base] = f2bf(w4.y);
            B_cv[2 * (size_t)CONV_PLANE + base] = f2bf(w4.z);
            B_cv[3 * (size_t)CONV_PLANE + base] = f2bf(w4.w);
            if (i == GCH - 1) {
                B_cv[0 * (size_t)CONV_PLANE + base + 1] = 0;
                B_cv[1 * (size_t)CONV_PLANE + base + 1] = 0;
                B_cv[2 * (size_t)CONV_PLANE + base + 1] = 0;
                B_cv[3 * (size_t)CONV_PLANE + base + 1] = 0;
            }
        }
        return;
    }

    const int w = tid >> 6, l = tid & 63;
    const int l15 = l & 15, l4 = l >> 4;
    const int wm = w >> 1, wn = w & 1;

    // bijective XCD-chunked swizzle (260 = 8*32+4); logical n-major.
    const int xcd = orig & 7, lo = orig >> 3;
    const int logical = (xcd < 4 ? xcd * 33 : 132 + (xcd - 4) * 32) + lo;
    int mt, nt, is_gate;
    if (logical < 180) { nt = logical / 9; mt = logical % 9; is_gate = 0; }
    else { int b2 = logical - 180; nt = 20 + b2 / 4; mt = 5 + b2 % 4; is_gate = 1; }
    const int m0 = mt * 128, n0 = nt * 128;

    // staging: seg = 16 rows (1KB); wave w stages A segs {w,w+4}, B segs {w,w+4}
    const int lr = l >> 2, slot = l & 3;
    const int r0 = w * 16 + lr, r1 = r0 + 64;
    const int xo0 = (slot ^ ((r0 >> 1) & 3)) << 3;
    const int xo1 = (slot ^ ((r1 >> 1) & 3)) << 3;
    const unsigned short* gA0 = A + (size_t)(m0 + r0) * DMODEL + xo0;
    const unsigned short* gA1 = A + (size_t)(m0 + r1) * DMODEL + xo1;
    const unsigned short* gB0 = B + (size_t)(n0 + r0) * DMODEL + xo0;
    const unsigned short* gB1 = B + (size_t)(n0 + r1) * DMODEL + xo1;
    unsigned short* dA0 = sm + w * 512;
    unsigned short* dA1 = sm + (w + 4) * 512;
    unsigned short* dB0 = sm + 4096 + w * 512;
    unsigned short* dB1 = sm + 4096 + (w + 4) * 512;

#define STAGE_G(buf, ks) do { int _o = (ks) * 32, _b = (buf) * 8192; \
    gload16(gA0 + _o, dA0 + _b); gload16(gA1 + _o, dA1 + _b); \
    gload16(gB0 + _o, dB0 + _b); gload16(gB1 + _o, dB1 + _b); } while (0)

    f32x4 acc[4][4] = {};
    auto compute = [&](const unsigned short* base) {
        bf16x8 af[4], bfr[4];
#pragma unroll
        for (int f = 0; f < 4; ++f)
            af[f] = *(const bf16x8*)(base + lds_addr(wm * 64 + f * 16 + l15, l4));
#pragma unroll
        for (int j = 0; j < 4; ++j)
            bfr[j] = *(const bf16x8*)(base + 4096 + lds_addr(wn * 64 + j * 16 + l15, l4));
        __builtin_amdgcn_s_setprio(1);
#pragma unroll
        for (int i = 0; i < 4; ++i)
#pragma unroll
            for (int j = 0; j < 4; ++j)
                acc[i][j] = __builtin_amdgcn_mfma_f32_16x16x32_bf16(af[i], bfr[j], acc[i][j], 0, 0, 0);
        __builtin_amdgcn_s_setprio(0);
    };

    STAGE_G(0, 0); STAGE_G(1, 1); STAGE_G(2, 2); STAGE_G(3, 3);
    int rbuf = 0, sbuf = 4;
    for (int ks = 0; ks < NKF - 4; ++ks) {
        asm volatile("s_waitcnt vmcnt(12)" ::: "memory");   // tile-ks loads done
        __builtin_amdgcn_s_barrier();
        STAGE_G(sbuf, ks + 4);                              // keep 4 tiles in flight
        compute(sm + rbuf * 8192);
        rbuf = rbuf == 4 ? 0 : rbuf + 1;
        sbuf = sbuf == 4 ? 0 : sbuf + 1;
    }
    asm volatile("s_waitcnt vmcnt(12)" ::: "memory");
    __builtin_amdgcn_s_barrier();
    compute(sm + rbuf * 8192); rbuf = rbuf == 4 ? 0 : rbuf + 1;
    asm volatile("s_waitcnt vmcnt(8)" ::: "memory");
    __builtin_amdgcn_s_barrier();
    compute(sm + rbuf * 8192); rbuf = rbuf == 4 ? 0 : rbuf + 1;
    asm volatile("s_waitcnt vmcnt(4)" ::: "memory");
    __builtin_amdgcn_s_barrier();
    compute(sm + rbuf * 8192); rbuf = rbuf == 4 ? 0 : rbuf + 1;
    asm volatile("s_waitcnt vmcnt(0)" ::: "memory");
    __builtin_amdgcn_s_barrier();
    compute(sm + rbuf * 8192);
#undef STAGE_G

    if (!is_gate) {
#pragma unroll
        for (int j = 0; j < 4; ++j) {
            int colg = n0 + wn * 64 + j * 16 + l15;
            if (colg < DINNER) {
                int g = colg / GCH, ci = colg - g * GCH;
                float bias = b_in[colg];
                size_t dco = (size_t)(g * GP + ci);
#pragma unroll
                for (int i = 0; i < 4; ++i)
#pragma unroll
                    for (int r = 0; r < 4; ++r) {
                        int row = m0 + wm * 64 + i * 16 + l4 * 4 + r;
                        xi[(size_t)row * NI + dco] = f2bf(acc[i][j][r] + bias);
                        if (ci == GCH - 1) xi[(size_t)row * NI + dco + 1] = 0;  // K-pad
                    }
            }
        }
    } else {
#pragma unroll
        for (int j = 0; j < 4; ++j) {
            int ng = n0 + wn * 64 + j * 16 + l15 - GATE0;
            if (ng < DINNER) {
                float bias = b_gate[ng];
#pragma unroll
                for (int i = 0; i < 4; ++i)
#pragma unroll
                    for (int r = 0; r < 4; ++r) {
                        int row = m0 + wm * 64 + i * 16 + l4 * 4 + r;  // >= 640 always
                        zb[(size_t)(row - 640) * NI + ng] = acc[i][j][r] + bias;
                    }
            }
        }
    }
}

// ---------------- grouped causal conv: 4 shifted-tap MFMA GEMMs + SiLU ------
// tile 64x128, 4 waves (wave-tile 32x64); depth-4 counted-vmcnt, 5 buffers.
#define NKC 44
__global__ __launch_bounds__(256)
void conv_mfma(const unsigned short* __restrict__ xi,  // [1152][NI] bf16
               const unsigned short* __restrict__ Bc,  // [4][2688][352] bf16
               const float* __restrict__ bc,
               float* __restrict__ xcb)                // [960][NI] f32 (post-SiLU)
{
    __shared__ unsigned short sm[5 * 192 * 32];   // 5 bufs x (A64 + B128 rows) x 64B = 60KB
    const int tid = threadIdx.x;
    const int w = tid >> 6, l = tid & 63;
    const int l15 = l & 15, l4 = l >> 4;
    const int wm = w >> 1, wn = w & 1;

    // bijective XCD-chunked swizzle (315 = 8*39+3)
    const int orig = blockIdx.x;
    const int xcd = orig & 7, lo = orig >> 3;
    const int logical = (xcd < 3 ? xcd * 40 : 120 + (xcd - 3) * 39) + lo;
    const int gn = logical / 15, mt = logical % 15;
    const int g = gn / 3, nt = gn % 3;
    const int m0 = mt * 64;
    const int n0l = nt * 128;

    const int lr = l >> 2, slot = l & 3;
    const int rA = w * 16 + lr;            // A rows 0..63 (seg w)
    const int rB1 = rA + 64;               // B segs w, w+4
    const int xoA  = (slot ^ ((rA  >> 1) & 3)) << 3;
    const int xoB1 = (slot ^ ((rB1 >> 1) & 3)) << 3;
    const unsigned short* gAb = xi + (size_t)(m0 + rA) * NI + g * GP + xoA;
    const unsigned short* gB0 = Bc + (size_t)(g * GNP + n0l + rA) * GP + xoA;
    const unsigned short* gB1 = Bc + (size_t)(g * GNP + n0l + rB1) * GP + xoB1;
    unsigned short* dA  = sm + w * 512;
    unsigned short* dB0 = sm + 2048 + w * 512;
    unsigned short* dB1 = sm + 2048 + (w + 4) * 512;

#define STAGE_C(buf, ks) do { \
    int _tap = (ks) / 11, _kc = (ks) - _tap * 11, _b = (buf) * 6144; \
    size_t _ao = (size_t)(64 * _tap) * NI + _kc * 32; \
    size_t _bo = (size_t)_tap * CONV_PLANE + _kc * 32; \
    gload16(gAb + _ao, dA  + _b); \
    gload16(gB0 + _bo, dB0 + _b); \
    gload16(gB1 + _bo, dB1 + _b); } while (0)

    f32x4 acc[2][4] = {};
    auto compute = [&](const unsigned short* base) {
        bf16x8 af[2], bfr[4];
#pragma unroll
        for (int f = 0; f < 2; ++f)
            af[f] = *(const bf16x8*)(base + lds_addr(wm * 32 + f * 16 + l15, l4));
#pragma unroll
        for (int j = 0; j < 4; ++j)
            bfr[j] = *(const bf16x8*)(base + 2048 + lds_addr(wn * 64 + j * 16 + l15, l4));
        __builtin_amdgcn_s_setprio(1);
#pragma unroll
        for (int i = 0; i < 2; ++i)
#pragma unroll
            for (int j = 0; j < 4; ++j)
                acc[i][j] = __builtin_amdgcn_mfma_f32_16x16x32_bf16(af[i], bfr[j], acc[i][j], 0, 0, 0);
        __builtin_amdgcn_s_setprio(0);
    };

    STAGE_C(0, 0); STAGE_C(1, 1); STAGE_C(2, 2); STAGE_C(3, 3);
    int rbuf = 0, sbuf = 4;
    for (int ks = 0; ks < NKC - 4; ++ks) {
        asm volatile("s_waitcnt vmcnt(9)" ::: "memory");
        __builtin_amdgcn_s_barrier();
        STAGE_C(sbuf, ks + 4);
        compute(sm + rbuf * 6144);
        rbuf = rbuf == 4 ? 0 : rbuf + 1;
        sbuf = sbuf == 4 ? 0 : sbuf + 1;
    }
    asm volatile("s_waitcnt vmcnt(9)" ::: "memory");
    __builtin_amdgcn_s_barrier();
    compute(sm + rbuf * 6144); rbuf = rbuf == 4 ? 0 : rbuf + 1;
    asm volatile("s_waitcnt vmcnt(6)" ::: "memory");
    __builtin_amdgcn_s_barrier();
    compute(sm + rbuf * 6144); rbuf = rbuf == 4 ? 0 : rbuf + 1;
    asm volatile("s_waitcnt vmcnt(3)" ::: "memory");
    __builtin_amdgcn_s_barrier();
    compute(sm + rbuf * 6144); rbuf = rbuf == 4 ? 0 : rbuf + 1;
    asm volatile("s_waitcnt vmcnt(0)" ::: "memory");
    __builtin_amdgcn_s_barrier();
    compute(sm + rbuf * 6144);
#undef STAGE_C

#pragma unroll
    for (int j = 0; j < 4; ++j) {
        int ocl = n0l + wn * 64 + j * 16 + l15;
        if (ocl < GCH) {
            int ch = g * GCH + ocl;
            float bias = bc[ch];
#pragma unroll
            for (int i = 0; i < 2; ++i)
#pragma unroll
                for (int r = 0; r < 4; ++r) {
                    int row = m0 + wm * 32 + i * 16 + l4 * 4 + r;
                    float v = acc[i][j][r] + bias;
                    xcb[(size_t)row * NI + ch] = v / (1.f + expf(-v));
                }
        }
    }
}

// ---------------- xp only: one block per row (512 rows, proven) ------------
__global__ __launch_bounds__(256)
void xp_kernel(const float* __restrict__ xc,    // [960][NI], rows 448.. = t 24..31
               const float* __restrict__ Wxp,   // [48][DINNER]
               const float* __restrict__ bxp,
               float* __restrict__ xp32)        // [512][32]
{
    const int row = blockIdx.x;
    const float* a = xc + (size_t)(448 + row) * NI;
    float acc[32];
#pragma unroll
    for (int o = 0; o < 32; ++o) acc[o] = 0.f;
    for (int k = threadIdx.x; k < DINNER; k += 256) {
        float av = a[k];
#pragma unroll
        for (int o = 0; o < 32; ++o)
            acc[o] = fmaf(av, Wxp[(size_t)o * DINNER + k], acc[o]);
    }
#pragma unroll
    for (int o = 0; o < 32; ++o)
#pragma unroll
        for (int off = 32; off; off >>= 1)
            acc[o] += __shfl_down(acc[o], off);
    __shared__ float red[4][32];
    const int wid = threadIdx.x >> 6, lane = threadIdx.x & 63;
    if (lane == 0)
#pragma unroll
        for (int o = 0; o < 32; ++o) red[wid][o] = acc[o];
    __syncthreads();
    if (threadIdx.x < 32) {
        int o = threadIdx.x;
        xp32[row * 32 + o] = red[0][o] + red[1][o] + red[2][o] + red[3][o] + bxp[o];
    }
}

// ---------------- window-softmax + inline dt + gate + mean over last 8 steps
__global__ __launch_bounds__(256)
void fuse_kernel(const float* __restrict__ xc, const float* __restrict__ z,
                 const float* __restrict__ xp,   // [512][32]
                 const float* __restrict__ Wdt,  // [DINNER][32]
                 const float* __restrict__ Dp,
                 float* __restrict__ comp)
{
    const int d = blockIdx.x * 256 + threadIdx.x;
    const int b = blockIdx.y;
    __shared__ float xps[8][32];
    {   // stage the 8 xp rows for this batch b (8*32 = 256 values, one per thread)
        int s = threadIdx.x >> 5, o = threadIdx.x & 31;
        xps[s][o] = xp[((s * 64) + b) * 32 + o];
    }
    __syncthreads();
    if (d >= DINNER) return;
    float wd[32];
    {
        const float4* wp = (const float4*)(Wdt + (size_t)d * 32);
#pragma unroll
        for (int q = 0; q < 8; ++q) {
            float4 v = wp[q];
            wd[q * 4 + 0] = v.x; wd[q * 4 + 1] = v.y;
            wd[q * 4 + 2] = v.z; wd[q * 4 + 3] = v.w;
        }
    }
    float xcv[15];
#pragma unroll
    for (int tt = 0; tt < 15; ++tt) xcv[tt] = xc[(size_t)(tt * 64 + b) * NI + d];
    const float Dpd = Dp[d];
    float acc = 0.f;
#pragma unroll
    for (int s = 0; s < 8; ++s) {
        float sv = 0.f;
#pragma unroll
        for (int k = 0; k < 32; ++k) sv = fmaf(xps[s][k], wd[k], sv);
        float dval = fmaxf(sv, 0.f) + log1pf(expf(-fabsf(sv))) + 1e-4f;  // softplus+eps
        float zval = z[(size_t)(s * 64 + b) * NI + d];
        float e = expf(-dval);
        float w = 1.f, wsum = 0.f, lsum = 0.f;
#pragma unroll
        for (int k = 7; k >= 0; --k) {
            wsum += w;
            lsum = fmaf(w, xcv[s + k], lsum);
            w *= e;
        }
        float local = lsum / wsum;
        float ys = (local + Dpd * xcv[s + 7]) / (1.f + expf(-zval));
        acc += ys;
    }
    comp[(size_t)b * NI + d] = acc * 0.125f;
}

// ---------------- split-K out-projection (f32)
__global__ __launch_bounds__(256)
void gemm_nt_splitk(const float* __restrict__ A, int lda,
                    const float* __restrict__ B, int ldb,
                    float* __restrict__ Cp, int ldc,
                    int M, int N, int K, int kchunk)
{
    __shared__ float As[16][68];
    __shared__ float Bs[16][68];
    const int tid = threadIdx.x;
    const int tx = tid & 15, ty = tid >> 4;
    const int m0 = blockIdx.y * 64, n0 = blockIdx.x * 64;
    const int kbeg = blockIdx.z * kchunk;
    const int kend = min(K, kbeg + kchunk);
    float* C = Cp + (size_t)blockIdx.z * M * ldc;
    float acc[4][4] = {};
    for (int k0 = kbeg; k0 < kend; k0 += 16) {
#pragma unroll
        for (int u = 0; u < 4; ++u) {
            int idx = u * 256 + tid;
            int r = idx >> 4, kk = idx & 15;
            int gk = k0 + kk;
            float av = 0.f, bv = 0.f;
            if (gk < kend) {
                av = A[(size_t)(m0 + r) * lda + gk];
                int nn = n0 + r;
                bv = (nn < N) ? B[(size_t)nn * ldb + gk] : 0.f;
            }
            As[kk][r] = av;
            Bs[kk][r] = bv;
        }
        __syncthreads();
#pragma unroll
        for (int kk = 0; kk < 16; ++kk) {
            float4 a4 = *(const float4*)&As[kk][ty * 4];
            float4 b4 = *(const float4*)&Bs[kk][tx * 4];
            float a[4] = {a4.x, a4.y, a4.z, a4.w};
            float b[4] = {b4.x, b4.y, b4.z, b4.w};
#pragma unroll
            for (int i = 0; i < 4; ++i)
#pragma unroll
                for (int j = 0; j < 4; ++j)
                    acc[i][j] = fmaf(a[i], b[j], acc[i][j]);
        }
        __syncthreads();
    }
#pragma unroll
    for (int i = 0; i < 4; ++i) {
        int m = m0 + ty * 4 + i;
#pragma unroll
        for (int j = 0; j < 4; ++j) {
            int n = n0 + tx * 4 + j;
            if (n < N) C[(size_t)m * ldc + n] = acc[i][j];
        }
    }
}

// ---------------- splitk-reduce + bias + layernorm fused (1024 threads) -----
__global__ __launch_bounds__(1024)
void ln_kernel(const float* __restrict__ Cp,    // [16][64][2048] partials
               const float* __restrict__ b_out,
               const float* __restrict__ lw, const float* __restrict__ lb,
               float* __restrict__ out)
{
    const int b = blockIdx.x;
    const int tid = threadIdx.x;     // 0..1023 (16 waves)
    __shared__ float red[16];
    float v[2];
    float s = 0.f;
#pragma unroll
    for (int i = 0; i < 2; ++i) {
        int col = i * 1024 + tid;
        float acc = b_out[col];
#pragma unroll
        for (int p = 0; p < OUT_SPLITS; ++p)
            acc += Cp[(size_t)p * 64 * 2048 + b * 2048 + col];
        v[i] = acc; s += acc;
    }
#pragma unroll
    for (int off = 32; off; off >>= 1) s += __shfl_down(s, off);
    if ((tid & 63) == 0) red[tid >> 6] = s;
    __syncthreads();
    float mu = 0.f;
#pragma unroll
    for (int q = 0; q < 16; ++q) mu += red[q];
    mu /= 2048.f;
    float s2 = 0.f;
#pragma unroll
    for (int i = 0; i < 2; ++i) { float dd = v[i] - mu; s2 += dd * dd; }
#pragma unroll
    for (int off = 32; off; off >>= 1) s2 += __shfl_down(s2, off);
    __syncthreads();
    if ((tid & 63) == 0) red[tid >> 6] = s2;
    __syncthreads();
    float var = 0.f;
#pragma unroll
    for (int q = 0; q < 16; ++q) var += red[q];
    var /= 2048.f;
    float inv = rsqrtf(var + 1e-5f);
#pragma unroll
    for (int i = 0; i < 2; ++i) {
        int dcol = i * 1024 + tid;
        out[b * 2048 + dcol] = (v[i] - mu) * inv * lw[dcol] + lb[dcol];
    }
}

extern "C" void kernel_launch(void* const* d_in, const int* in_sizes, int n_in,
                              void* d_out, int out_size, void* d_ws, size_t ws_size,
                              hipStream_t stream)
{
    const float* x      = (const float*)d_in[0];
    const float* W_in   = (const float*)d_in[1];
    const float* b_in   = (const float*)d_in[2];
    const float* W_gate = (const float*)d_in[3];
    const float* b_gate = (const float*)d_in[4];
    const float* W_conv = (const float*)d_in[5];
    const float* b_conv = (const float*)d_in[6];
    const float* W_xp   = (const float*)d_in[7];
    const float* b_xp   = (const float*)d_in[8];
    const float* W_dt   = (const float*)d_in[9];
    const float* Dp     = (const float*)d_in[10];
    const float* W_out  = (const float*)d_in[11];
    const float* b_out  = (const float*)d_in[12];
    const float* ln_w   = (const float*)d_in[13];
    const float* ln_b   = (const float*)d_in[14];
    float* out = (float*)d_out;

    float* ws = (float*)d_ws;
    auto alloc = [&](size_t nf) { float* p = ws; ws += (nf + 255) & ~(size_t)255; return p; };
    unsigned short* A_x   = (unsigned short*)alloc((size_t)NROW_XI * DMODEL / 2);
    unsigned short* B_cat = (unsigned short*)alloc((size_t)NCAT * DMODEL / 2);
    unsigned short* B_cv  = (unsigned short*)alloc((size_t)4 * CONV_PLANE / 2);
    unsigned short* xi_bf = (unsigned short*)alloc((size_t)NROW_XI * NI / 2);
    float* zb   = alloc((size_t)NROW_Z * NI);
    float* xp32 = alloc((size_t)512 * 32);
    float* comp = alloc((size_t)64 * NI);
    // aliases (stream-ordered lifetime):
    float* xcb     = (float*)B_cat;                    // 960*NI f32, after fused GEMM done
    float* outpart = (float*)B_cat + (size_t)960 * NI; // 16*64*2048 f32, disjoint from xcb

    // 1) casts (x slice + W_in|W_gate); conv weights cast inside gemm kernel
    cast_all<<<CAST_B1, 256, 0, stream>>>(x + (size_t)(110 * 64) * DMODEL,
                                          W_in, W_gate, A_x, B_cat);
    // 2) fused xi|z MFMA GEMM (260 tiles) + overlapped conv-weight cast (224 blocks)
    gemm_mfma_fused<<<GEMM_BLKS + CAST_BLKS, 256, 0, stream>>>(
        A_x, B_cat, W_conv, b_in, b_gate, xi_bf, zb, B_cv);
    // 3) conv MFMA + SiLU
    conv_mfma<<<315, 256, 0, stream>>>(xi_bf, B_cv, b_conv, xcb);
    // 4) xp projection, then window-softmax fuse with inline dt
    xp_kernel<<<512, 256, 0, stream>>>(xcb, W_xp, b_xp, xp32);
    {
        dim3 grid((DINNER + 255) / 256, 64);
        fuse_kernel<<<grid, 256, 0, stream>>>(xcb, zb, xp32, W_dt, Dp, comp);
    }
    // 5) out-projection (split-K 16) + fused reduce+LN (1024-thread blocks)
    {
        const int kchunk = (DINNER + OUT_SPLITS - 1) / OUT_SPLITS;  // 154
        dim3 grid(DMODEL / 64, 1, OUT_SPLITS);
        gemm_nt_splitk<<<grid, 256, 0, stream>>>(comp, NI, W_out, DINNER,
                                                 outpart, DMODEL, 64, DMODEL, DINNER, kchunk);
    }
    ln_kernel<<<64, 1024, 0, stream>>>(outpart, b_out, ln_w, ln_b, out);
}